// Round 12
// baseline (977.549 us; speedup 1.0000x reference)
//
#include <hip/hip_runtime.h>
#include <hip/hip_bf16.h>
#include <math.h>

#define T_   64
#define B_   2048
#define OBS_ 48
#define H_   256
#define M1_  512
#define M2_  256
#define A_   12
#define BH_  (B_ * H_)
#define KP_  320   // padded K for scan: 64 (x, padded from 48) + 256 (h)

typedef unsigned short u16;
typedef __attribute__((ext_vector_type(8))) short bf16x8;
typedef __attribute__((ext_vector_type(4))) float f32x4;

static __device__ __forceinline__ u16 f2b(float f) {
    __hip_bfloat16 h = __float2bfloat16(f);
    return *reinterpret_cast<u16*>(&h);
}
static __device__ __forceinline__ float b2f(u16 u) {
    union { unsigned u32v; float f; } v; v.u32v = ((unsigned)u) << 16; return v.f;
}
static __device__ __forceinline__ float sigm(float x) {
    return 1.0f / (1.0f + __expf(-x));
}
static __device__ __forceinline__ float tanh_fast(float x) {
    x = fminf(fmaxf(x, -15.0f), 15.0f);
    float e = __expf(2.0f * x);
    return (e - 1.0f) / (e + 1.0f);
}
static __device__ __forceinline__ float elu(float x) {
    return x > 0.0f ? x : (__expf(x) - 1.0f);
}

// ---------------------------------------------------------------------------
// Pre-pass kernels
// ---------------------------------------------------------------------------
__global__ void prep_xpad(const float* __restrict__ x, u16* __restrict__ xpad) {
    const int gid = blockIdx.x * 256 + threadIdx.x;   // T*B*8 threads
    const int r = gid >> 3, k0 = (gid & 7) * 8;
    u16 tmp[8];
    if (k0 < OBS_) {
        const float4 f0 = *(const float4*)(x + (size_t)r * OBS_ + k0);
        const float4 f1 = *(const float4*)(x + (size_t)r * OBS_ + k0 + 4);
        tmp[0] = f2b(f0.x); tmp[1] = f2b(f0.y); tmp[2] = f2b(f0.z); tmp[3] = f2b(f0.w);
        tmp[4] = f2b(f1.x); tmp[5] = f2b(f1.y); tmp[6] = f2b(f1.z); tmp[7] = f2b(f1.w);
    } else {
        #pragma unroll
        for (int i = 0; i < 8; ++i) tmp[i] = 0;
    }
    *(uint4*)(xpad + (size_t)gid * 8) = *(uint4*)tmp;
}

// W1S/W2S: per-chunk-linear staged tiles, flat idx f = ((ph*8+c)*4+q)*2048 + n*8 + e
//   W1S[f] = W1[k][ph*256+n], k = c*32+q*8+e   (W1 is [256][512] k-major)
//   W2S[f] = W2[ph*256+k][n]                   (W2 is [512][256])
__global__ void prep_weights(const float* __restrict__ W_ih, const float* __restrict__ W_hh,
                             const float* __restrict__ W1,  const float* __restrict__ W2,
                             const float* __restrict__ Wm,  const float* __restrict__ Ws,
                             u16* __restrict__ Wcat, u16* __restrict__ W1S,
                             u16* __restrict__ W2S,  u16* __restrict__ WhT) {
    const int b = blockIdx.x, tid = threadIdx.x;
    if (b < 1024) {
        for (int k = tid; k < KP_; k += 256) {
            float v;
            if (k < OBS_)    v = W_ih[b * OBS_ + k];
            else if (k < 64) v = 0.0f;
            else             v = W_hh[b * H_ + (k - 64)];
            Wcat[b * KP_ + k] = f2b(v);
        }
    } else if (b < 2048) {
        const int f  = ((b - 1024) & 511) * 256 + tid;   // 0..131071
        const int e  = f & 7;
        const int n  = (f >> 3) & 255;
        const int q  = (f >> 11) & 3;
        const int c  = (f >> 13) & 7;
        const int ph = (f >> 16) & 1;
        const int k  = c * 32 + q * 8 + e;
        if (b < 1536) W1S[f] = f2b(W1[k * M1_ + ph * 256 + n]);
        else          W2S[f] = f2b(W2[(ph * 256 + k) * M2_ + n]);
    } else {
        const int n = b - 2048;                       // WhT [32][256]
        float v = 0.0f;
        if (n < 12)                 v = Wm[tid * A_ + n];
        else if (n >= 16 && n < 28) v = Ws[tid * A_ + (n - 16)];
        WhT[n * 256 + tid] = f2b(v);
    }
}

__global__ void init_state2(const float* __restrict__ h0, const float* __restrict__ c0,
                            u16* __restrict__ hs0, float* __restrict__ Cst) {
    const int i = blockIdx.x * 256 + threadIdx.x;
    hs0[i] = f2b(h0[i]);
    Cst[i] = c0[i];
}

// ---------------------------------------------------------------------------
// LSTM step (round-4/7 kernel, known-good ~11.25 us/step incl. dispatch).
// ---------------------------------------------------------------------------
#define ASM_(row, chunk) (a_sm + (size_t)(row) * 320 + (size_t)(((chunk) ^ ((row) & 7)) << 3))

__global__ __launch_bounds__(256, 2) void lstm_step4(
    const u16*  __restrict__ xpad_t,  // [B][64]
    const int*  __restrict__ done_t,  // [B]
    const u16*  __restrict__ Hin,     // [B][256] bf16
    u16*        __restrict__ Hout,    // [B][256] bf16
    float*      __restrict__ Cst,     // [B][256] fp32, in-place
    const u16*  __restrict__ Wcat,    // [1024][320]
    const float* __restrict__ b_ih,
    const float* __restrict__ b_hh)
{
    __shared__ u16   a_sm[64 * 320];   // 40 KB, XOR-swizzled
    __shared__ float g_sm[64][68];     // 17.4 KB
    __shared__ float keep_sm[64];

    const int tid  = threadIdx.x;
    const int lane = tid & 63;
    const int wave = tid >> 6;
    const int wm = wave & 1, wn = wave >> 1;
    const int quad = lane >> 4, l16 = lane & 15;
    const int b0 = blockIdx.x * 64;
    const int j0 = blockIdx.y * 16;

    bf16x8 Bf0[10], Bf1[10];
    {
        const u16* wp0 = Wcat + ((size_t)((wn * 2 + 0) * 256 + j0 + l16)) * KP_ + quad * 8;
        const u16* wp1 = Wcat + ((size_t)((wn * 2 + 1) * 256 + j0 + l16)) * KP_ + quad * 8;
        #pragma unroll
        for (int kt = 0; kt < 10; ++kt) {
            Bf0[kt] = *(const bf16x8*)(wp0 + kt * 32);
            Bf1[kt] = *(const bf16x8*)(wp1 + kt * 32);
        }
    }

    if (tid < 64) keep_sm[tid] = done_t[b0 + tid] ? 0.0f : 1.0f;
    {
        const int srow = tid >> 2;
        const int sseg = tid & 3;
        const u16* xrow = xpad_t + (size_t)(b0 + srow) * 64;
        const uint4 xv0 = *(const uint4*)(xrow + sseg * 8);
        const uint4 xv1 = *(const uint4*)(xrow + (sseg + 4) * 8);
        *(uint4*)ASM_(srow, sseg)     = xv0;
        *(uint4*)ASM_(srow, sseg + 4) = xv1;

        const int dn = done_t[b0 + srow];
        const u16* hrow = Hin + (size_t)(b0 + srow) * H_ + sseg * 64;
        #pragma unroll
        for (int i = 0; i < 8; ++i) {
            uint4 hv = *(const uint4*)(hrow + i * 8);
            if (dn) hv = make_uint4(0u, 0u, 0u, 0u);
            *(uint4*)ASM_(srow, 8 + sseg * 8 + i) = hv;
        }
    }
    __syncthreads();

    f32x4 acc00 = {0,0,0,0}, acc01 = {0,0,0,0}, acc10 = {0,0,0,0}, acc11 = {0,0,0,0};
    #pragma unroll
    for (int kt = 0; kt < 10; ++kt) {
        const bf16x8 af0 = *(const bf16x8*)ASM_(wm * 32 +  0 + l16, kt * 4 + quad);
        const bf16x8 af1 = *(const bf16x8*)ASM_(wm * 32 + 16 + l16, kt * 4 + quad);
        acc00 = __builtin_amdgcn_mfma_f32_16x16x32_bf16(af0, Bf0[kt], acc00, 0, 0, 0);
        acc01 = __builtin_amdgcn_mfma_f32_16x16x32_bf16(af0, Bf1[kt], acc01, 0, 0, 0);
        acc10 = __builtin_amdgcn_mfma_f32_16x16x32_bf16(af1, Bf0[kt], acc10, 0, 0, 0);
        acc11 = __builtin_amdgcn_mfma_f32_16x16x32_bf16(af1, Bf1[kt], acc11, 0, 0, 0);
    }

    #pragma unroll
    for (int r = 0; r < 4; ++r) {
        g_sm[wm * 32 +  0 + quad * 4 + r][wn * 32 +  0 + l16] = acc00[r];
        g_sm[wm * 32 +  0 + quad * 4 + r][wn * 32 + 16 + l16] = acc01[r];
        g_sm[wm * 32 + 16 + quad * 4 + r][wn * 32 +  0 + l16] = acc10[r];
        g_sm[wm * 32 + 16 + quad * 4 + r][wn * 32 + 16 + l16] = acc11[r];
    }
    __syncthreads();

    const int jj = tid & 15, bq = tid >> 4;
    const int jg = j0 + jj;
    const float bi_b = b_ih[jg]       + b_hh[jg];
    const float bf_b = b_ih[256 + jg] + b_hh[256 + jg];
    const float bg_b = b_ih[512 + jg] + b_hh[512 + jg];
    const float bo_b = b_ih[768 + jg] + b_hh[768 + jg];
    #pragma unroll
    for (int r = 0; r < 4; ++r) {
        const int b = bq * 4 + r;
        const float gi = g_sm[b][jj]      + bi_b;
        const float gf = g_sm[b][16 + jj] + bf_b;
        const float gg = g_sm[b][32 + jj] + bg_b;
        const float go = g_sm[b][48 + jj] + bo_b;
        const size_t idx = (size_t)(b0 + b) * H_ + jg;
        const float cold = Cst[idx] * keep_sm[b];
        const float cn = sigm(gf) * cold + sigm(gi) * tanh_fast(gg);
        Cst[idx] = cn;
        Hout[idx] = f2b(sigm(go) * tanh_fast(cn));
    }
}

// ---------------------------------------------------------------------------
// MLP v6: 128 rows/block; B-tiles STAGED IN LDS (m97 pattern). Per K=32 chunk:
// barrier -> ds_write 16 KB tile (prefetched into regs, next chunk's loads
// issued under compute) -> barrier -> MFMA from LDS only. Kills the per-kt
// L2-latency dependency that capped MfmaUtil at 14% in r7/r11 (compiler
// refused register pipelining: VGPR=64, ring prefetch re-sunk).
// LDS: ybf 64K + yh 64K + bt 16K = 144 KB dynamic.
// ---------------------------------------------------------------------------
#define SY(row, col) ((size_t)(row) * 256 + ((((col) >> 3) ^ ((row) & 7)) << 3) + ((col) & 7))

__global__ __launch_bounds__(512, 2) void mlp_v6(
    const u16*  __restrict__ hs,    // [nrows][256] bf16
    float*      __restrict__ out,   // [nrows][14]
    const float* __restrict__ lng, const float* __restrict__ lnb,
    const u16*  __restrict__ W1S, const float* __restrict__ b1,
    const u16*  __restrict__ W2S, const float* __restrict__ b2,
    const u16*  __restrict__ WhT,
    const float* __restrict__ bm, const float* __restrict__ bs)
{
    extern __shared__ u16 smem[];
    u16* ybf = smem;                 // [128*256]: LN output, later y2
    u16* yh  = smem + 32768;         // [128*256]: y1 column-half; later ls overlay
    u16* bt  = smem + 65536;         // [8192]: staged B-tile (chunk): [q][n][8]

    const int tid  = threadIdx.x;
    const int lane = tid & 63;
    const int wave = tid >> 6;        // 0..7
    const int quad = lane >> 4, l16 = lane & 15;
    const int row0 = blockIdx.x * 128;

    // ---- LayerNorm: wave w -> rows w*16..w*16+15 ----
    {
        const float4 gv = *(const float4*)(lng + lane * 4);
        const float4 bv = *(const float4*)(lnb + lane * 4);
        #pragma unroll
        for (int rr = 0; rr < 16; ++rr) {
            const int r = wave * 16 + rr;
            const ushort4 hv = *(const ushort4*)(hs + (size_t)(row0 + r) * H_ + lane * 4);
            const float v0 = b2f(hv.x), v1 = b2f(hv.y), v2 = b2f(hv.z), v3 = b2f(hv.w);
            float s  = v0 + v1 + v2 + v3;
            float ss = v0 * v0 + v1 * v1 + v2 * v2 + v3 * v3;
            #pragma unroll
            for (int off = 32; off > 0; off >>= 1) {
                s  += __shfl_down(s,  off);
                ss += __shfl_down(ss, off);
            }
            s = __shfl(s, 0); ss = __shfl(ss, 0);
            const float mu   = s * (1.0f / 256.0f);
            const float rstd = rsqrtf(ss * (1.0f / 256.0f) - mu * mu + 1e-5f);
            ushort4 o;
            o.x = f2b((v0 - mu) * rstd * gv.x + bv.x);
            o.y = f2b((v1 - mu) * rstd * gv.y + bv.y);
            o.z = f2b((v2 - mu) * rstd * gv.z + bv.z);
            o.w = f2b((v3 - mu) * rstd * gv.w + bv.w);
            *(ushort4*)(ybf + SY(r, lane * 4)) = o;
        }
    }

    f32x4 acc2[8][2];
    #pragma unroll
    for (int m = 0; m < 8; ++m)
        #pragma unroll
        for (int j = 0; j < 2; ++j) acc2[m][j] = (f32x4){0,0,0,0};

    const int nA = wave * 32 + l16;         // B-frag col 0 for this wave
    const int nB = wave * 32 + 16 + l16;    // B-frag col 1

    #pragma unroll
    for (int ph = 0; ph < 2; ++ph) {
        // ================= L1: y1 cols [ph*256 + wave*32, +32) =================
        {
            f32x4 acc[8][2];
            #pragma unroll
            for (int m = 0; m < 8; ++m)
                #pragma unroll
                for (int j = 0; j < 2; ++j) acc[m][j] = (f32x4){0,0,0,0};
            const u16* wsrc = W1S + ((size_t)(ph * 8) << 13);
            uint4 p0 = *(const uint4*)(wsrc + tid * 16);
            uint4 p1 = *(const uint4*)(wsrc + tid * 16 + 8);
            #pragma unroll
            for (int c = 0; c < 8; ++c) {
                __syncthreads();                  // bt free (prev chunk consumed)
                *(uint4*)(bt + tid * 16)     = p0;
                *(uint4*)(bt + tid * 16 + 8) = p1;
                if (c < 7) {                      // prefetch next chunk under compute
                    p0 = *(const uint4*)(wsrc + ((size_t)(c + 1) << 13) + tid * 16);
                    p1 = *(const uint4*)(wsrc + ((size_t)(c + 1) << 13) + tid * 16 + 8);
                }
                __syncthreads();                  // staged tile visible
                const int k0 = c * 32;
                const bf16x8 bw0 = *(const bf16x8*)(bt + quad * 2048 + nA * 8);
                const bf16x8 bw1 = *(const bf16x8*)(bt + quad * 2048 + nB * 8);
                #pragma unroll
                for (int m = 0; m < 8; ++m) {
                    const bf16x8 af = *(const bf16x8*)(ybf + SY(m * 16 + l16, k0 + quad * 8));
                    acc[m][0] = __builtin_amdgcn_mfma_f32_16x16x32_bf16(af, bw0, acc[m][0], 0, 0, 0);
                    acc[m][1] = __builtin_amdgcn_mfma_f32_16x16x32_bf16(af, bw1, acc[m][1], 0, 0, 0);
                }
            }
            const float bb0 = b1[ph * 256 + nA], bb1 = b1[ph * 256 + nB];
            __syncthreads();   // all waves past L2(ph-1) reads of yh
            #pragma unroll
            for (int m = 0; m < 8; ++m)
                #pragma unroll
                for (int r = 0; r < 4; ++r) {
                    const int row = m * 16 + quad * 4 + r;
                    yh[SY(row, wave * 32 + l16)]      = f2b(elu(acc[m][0][r] + bb0));
                    yh[SY(row, wave * 32 + 16 + l16)] = f2b(elu(acc[m][1][r] + bb1));
                }
        }

        // ================= L2 partial: K in [ph*256, +256) =================
        {
            const u16* wsrc = W2S + ((size_t)(ph * 8) << 13);
            uint4 p0 = *(const uint4*)(wsrc + tid * 16);
            uint4 p1 = *(const uint4*)(wsrc + tid * 16 + 8);
            #pragma unroll
            for (int c = 0; c < 8; ++c) {
                __syncthreads();                  // bt free AND y1 writes visible (c==0)
                *(uint4*)(bt + tid * 16)     = p0;
                *(uint4*)(bt + tid * 16 + 8) = p1;
                if (c < 7) {
                    p0 = *(const uint4*)(wsrc + ((size_t)(c + 1) << 13) + tid * 16);
                    p1 = *(const uint4*)(wsrc + ((size_t)(c + 1) << 13) + tid * 16 + 8);
                }
                __syncthreads();
                const int k0 = c * 32;
                const bf16x8 bw0 = *(const bf16x8*)(bt + quad * 2048 + nA * 8);
                const bf16x8 bw1 = *(const bf16x8*)(bt + quad * 2048 + nB * 8);
                #pragma unroll
                for (int m = 0; m < 8; ++m) {
                    const bf16x8 af = *(const bf16x8*)(yh + SY(m * 16 + l16, k0 + quad * 8));
                    acc2[m][0] = __builtin_amdgcn_mfma_f32_16x16x32_bf16(af, bw0, acc2[m][0], 0, 0, 0);
                    acc2[m][1] = __builtin_amdgcn_mfma_f32_16x16x32_bf16(af, bw1, acc2[m][1], 0, 0, 0);
                }
            }
        }
    }

    // ---- y2 = elu(acc2 + b2) -> ybf ----
    __syncthreads();
    {
        const float bb0 = b2[nA], bb1 = b2[nB];
        #pragma unroll
        for (int m = 0; m < 8; ++m)
            #pragma unroll
            for (int r = 0; r < 4; ++r) {
                const int row = m * 16 + quad * 4 + r;
                ybf[SY(row, wave * 32 + l16)]      = f2b(elu(acc2[m][0][r] + bb0));
                ybf[SY(row, wave * 32 + 16 + l16)] = f2b(elu(acc2[m][1][r] + bb1));
            }
    }
    __syncthreads();

    // ---- Heads: wave = m-frag (8 waves x 16 rows); WhT direct from L2 ----
    float* lsf = (float*)yh;   // overlay: [128][16] floats
    {
        f32x4 a0 = {0,0,0,0}, a1 = {0,0,0,0};
        const u16* wp0 = WhT + (size_t)l16 * 256 + quad * 8;
        const u16* wp1 = WhT + (size_t)(16 + l16) * 256 + quad * 8;
        #pragma unroll
        for (int kt = 0; kt < 8; ++kt) {
            const int k0 = kt * 32;
            const bf16x8 af  = *(const bf16x8*)(ybf + SY(wave * 16 + l16, k0 + quad * 8));
            const bf16x8 bw0 = *(const bf16x8*)(wp0 + k0);
            const bf16x8 bw1 = *(const bf16x8*)(wp1 + k0);
            a0 = __builtin_amdgcn_mfma_f32_16x16x32_bf16(af, bw0, a0, 0, 0, 0);
            a1 = __builtin_amdgcn_mfma_f32_16x16x32_bf16(af, bw1, a1, 0, 0, 0);
        }
        if (l16 < 12) {
            const float bbm = bm[l16], bbs = bs[l16];
            #pragma unroll
            for (int r = 0; r < 4; ++r) {
                const int row = wave * 16 + quad * 4 + r;
                out[(size_t)(row0 + row) * 14 + l16] = a0[r] + bbm;
                lsf[row * 16 + l16] = fminf(fmaxf(a1[r] + bbs, -5.0f), 2.0f);
            }
        }
    }
    __syncthreads();
    if (tid < 128) {
        float s = 0.0f;
        #pragma unroll
        for (int q = 0; q < 12; ++q) s += lsf[tid * 16 + q];
        const float LOG2PI = 1.8378770664093453f;
        out[(size_t)(row0 + tid) * 14 + 12] = -s - 6.0f * LOG2PI;
        out[(size_t)(row0 + tid) * 14 + 13] =  s + 6.0f + 6.0f * LOG2PI;
    }
}

// ---------------------------------------------------------------------------
extern "C" void kernel_launch(void* const* d_in, const int* in_sizes, int n_in,
                              void* d_out, int out_size, void* d_ws, size_t ws_size,
                              hipStream_t stream) {
    (void)in_sizes; (void)n_in; (void)out_size; (void)ws_size;
    const float* x    = (const float*)d_in[0];
    const int*   done = (const int*)  d_in[1];
    const float* h0   = (const float*)d_in[2];
    const float* c0   = (const float*)d_in[3];
    const float* W_ih = (const float*)d_in[4];
    const float* W_hh = (const float*)d_in[5];
    const float* b_ih = (const float*)d_in[6];
    const float* b_hh = (const float*)d_in[7];
    const float* lng  = (const float*)d_in[8];
    const float* lnb  = (const float*)d_in[9];
    const float* W1   = (const float*)d_in[10];
    const float* b1   = (const float*)d_in[11];
    const float* W2   = (const float*)d_in[12];
    const float* b2   = (const float*)d_in[13];
    const float* Wm   = (const float*)d_in[14];
    const float* bm   = (const float*)d_in[15];
    const float* Ws   = (const float*)d_in[16];
    const float* bs   = (const float*)d_in[17];
    float* out = (float*)d_out;

    // workspace carve (~37 MB; ws_size >= 135 MB confirmed)
    unsigned char* p = (unsigned char*)d_ws;
    u16* hs    = (u16*)p;              p += (size_t)(T_ + 1) * BH_ * 2;
    u16* xpad  = (u16*)p;              p += (size_t)T_ * B_ * 64 * 2;
    u16* Wcat  = (u16*)p;              p += (size_t)1024 * KP_ * 2;
    u16* W1S   = (u16*)p;              p += (size_t)M1_ * H_ * 2;
    u16* W2S   = (u16*)p;              p += (size_t)M2_ * M1_ * 2;
    u16* WhT   = (u16*)p;              p += (size_t)32 * H_ * 2;
    float* Cst = (float*)p;            p += (size_t)BH_ * 4;

    // allow 144 KB dynamic LDS for the MLP (idempotent, graph-capture-safe)
    hipFuncSetAttribute((const void*)mlp_v6,
                        hipFuncAttributeMaxDynamicSharedMemorySize, 147456);

    prep_xpad<<<(T_ * B_ * 8) / 256, 256, 0, stream>>>(x, xpad);
    prep_weights<<<2080, 256, 0, stream>>>(W_ih, W_hh, W1, W2, Wm, Ws,
                                           Wcat, W1S, W2S, WhT);
    init_state2<<<BH_ / 256, 256, 0, stream>>>(h0, c0, hs, Cst);

    for (int t = 0; t < T_; ++t) {
        lstm_step4<<<dim3(32, 16), 256, 0, stream>>>(
            xpad + (size_t)t * B_ * 64,
            done + (size_t)t * B_,
            hs + (size_t)t * BH_,
            hs + (size_t)(t + 1) * BH_,
            Cst, Wcat, b_ih, b_hh);
    }

    mlp_v6<<<(T_ * B_) / 128, 512, 147456, stream>>>(
        hs + BH_, out, lng, lnb, W1S, b1, W2S, b2, WhT, bm, bs);
}